// Round 1
// baseline (116.982 us; speedup 1.0000x reference)
//
#include <hip/hip_runtime.h>
#include <hip/hip_bf16.h>
#include <cstdint>

// Conv2d 3x3 s1 p1, NCHW fp32 -> implicit GEMM on bf16 MFMA.
// x: [32][128][56][56] f32, filters: [256][128][3][3] f32, biases: [256] f32
// out: [32][256][56][56] f32
//
// ws layout: Xp (NHWC padded bf16 [32][58][58][128]) then Wt (bf16 [9][256][128]).

typedef __bf16 bf16x8 __attribute__((ext_vector_type(8)));
typedef float f32x4 __attribute__((ext_vector_type(4)));

#define XP_ELEMS (32 * 430592)            // 58*58*128 per image
#define XP_BYTES (XP_ELEMS * 2)           // 27,557,888
#define WT_ELEMS (9 * 256 * 128)          // 294,912

__device__ __forceinline__ unsigned short f2bf(float f) {
  __bf16 b = (__bf16)f;
  return __builtin_bit_cast(unsigned short, b);
}

__device__ __forceinline__ void gload16(const void* g, void* l) {
  __builtin_amdgcn_global_load_lds(
      (const __attribute__((address_space(1))) unsigned int*)g,
      (__attribute__((address_space(3))) unsigned int*)l,
      16, 0, 0);
}

// ---- prep: x NCHW f32 -> padded NHWC bf16 ------------------------------
__global__ __launch_bounds__(256) void prep_x(const float* __restrict__ x,
                                              unsigned short* __restrict__ xp) {
  __shared__ unsigned short lt[64][34];  // [hw][c] tile, padded stride
  int b = blockIdx.x;
  int hwt = b % 49;          // 49 tiles of 64 hw positions
  int ct  = (b / 49) & 3;    // 4 tiles of 32 channels
  int n   = b / 196;
  int t = threadIdx.x;
  int c_loc = t >> 3, col8 = t & 7;
  int hw0 = hwt << 6, c0 = ct << 5;

  const float* src = x + ((n * 128 + c0 + c_loc) * 3136 + hw0 + (col8 << 3));
  float4 v0 = *(const float4*)src;
  float4 v1 = *(const float4*)(src + 4);
  int hb = col8 << 3;
  lt[hb + 0][c_loc] = f2bf(v0.x);
  lt[hb + 1][c_loc] = f2bf(v0.y);
  lt[hb + 2][c_loc] = f2bf(v0.z);
  lt[hb + 3][c_loc] = f2bf(v0.w);
  lt[hb + 4][c_loc] = f2bf(v1.x);
  lt[hb + 5][c_loc] = f2bf(v1.y);
  lt[hb + 6][c_loc] = f2bf(v1.z);
  lt[hb + 7][c_loc] = f2bf(v1.w);
  __syncthreads();

  int hwl = t >> 2, cs = t & 3;
  const unsigned int* lr = (const unsigned int*)&lt[hwl][cs << 3];
  uint4 o = make_uint4(lr[0], lr[1], lr[2], lr[3]);
  int hw = hw0 + hwl;
  int hp = hw / 56 + 1, wp = hw % 56 + 1;
  unsigned short* dst = xp + (n * 430592 + (hp * 58 + wp) * 128 + c0 + (cs << 3));
  *(uint4*)dst = o;
}

// ---- prep: filters OIHW f32 -> Wt[9][256][128] bf16 --------------------
__global__ __launch_bounds__(256) void prep_w(const float* __restrict__ f,
                                              unsigned short* __restrict__ wt) {
  int idx = blockIdx.x * 256 + threadIdx.x;  // < 294912
  int c = idx & 127;
  int k = (idx >> 7) & 255;
  int rs = idx >> 15;
  wt[idx] = f2bf(f[(k * 128 + c) * 9 + rs]);
}

// ---- main: implicit GEMM -----------------------------------------------
// Block: 256 thr = 4 waves (2x2), tile BM=128 (k) x BN=128 (p). K-step 32.
__global__ __launch_bounds__(256) void conv_mfma(const unsigned short* __restrict__ xp,
                                                 const unsigned short* __restrict__ wt,
                                                 const float* __restrict__ bias,
                                                 float* __restrict__ out) {
  __shared__ unsigned short Asm[128 * 32];  // [row k][32 c], 16B-slot swizzled
  __shared__ unsigned short Bsm[128 * 32];  // [row p][32 c], 16B-slot swizzled
  int bid = blockIdx.x;
  int mt = bid & 1;         // 2 M-tiles
  int pt = bid >> 1;        // 784 P-tiles
  int t = threadIdx.x;
  int wv = t >> 6, l = t & 63;

  // staging: each lane loads 16B; row = wv*16 + l/4 (+64 for chunk 1), slot = l&3.
  // LDS slot s holds DATA[row][s ^ f(row)], f(row)=(row>>1)&3  -> pre-swizzle source.
  int rowA0 = (wv << 4) + (l >> 2);
  int rowA1 = rowA0 + 64;
  int slot = l & 3;
  int sd0 = slot ^ ((rowA0 >> 1) & 3);
  int sd1 = slot ^ ((rowA1 >> 1) & 3);

  const unsigned short* srcA0 = wt + ((mt * 128 + rowA0) << 7) + (sd0 << 3);
  const unsigned short* srcA1 = wt + ((mt * 128 + rowA1) << 7) + (sd1 << 3);

  int pB0 = (pt << 7) + rowA0;
  int pB1 = pB0 + 64;
  int n0 = pB0 / 3136, hw0 = pB0 % 3136;
  int n1 = pB1 / 3136, hw1 = pB1 % 3136;
  const unsigned short* srcB0 =
      xp + (n0 * 430592 + ((hw0 / 56) * 58 + (hw0 % 56)) * 128 + (sd0 << 3));
  const unsigned short* srcB1 =
      xp + (n1 * 430592 + ((hw1 / 56) * 58 + (hw1 % 56)) * 128 + (sd1 << 3));

  char* ldsA = (char*)Asm;
  char* ldsB = (char*)Bsm;
  char* dA0 = ldsA + (wv << 10);
  char* dA1 = ldsA + 4096 + (wv << 10);
  char* dB0 = ldsB + (wv << 10);
  char* dB1 = ldsB + 4096 + (wv << 10);

  // fragment reads: row = base + (l&15), slot_read = (l>>4) ^ f(row)
  int r15 = l & 15, hi = l >> 4;
  int srd = hi ^ ((r15 >> 1) & 3);
  int wr = wv >> 1, wc = wv & 1;
  int aoff = ((wr << 6) + r15) * 64 + (srd << 4);
  int boff = ((wc << 6) + r15) * 64 + (srd << 4);

  f32x4 acc[4][4];
#pragma unroll
  for (int m = 0; m < 4; ++m)
#pragma unroll
    for (int n = 0; n < 4; ++n) acc[m][n] = (f32x4){0.f, 0.f, 0.f, 0.f};

#pragma unroll 1
  for (int rs = 0; rs < 9; ++rs) {
    int offA = rs << 15;                               // rs * 256*128
    int offB = ((rs / 3) * 58 + (rs % 3)) << 7;        // (r*58+s)*128
#pragma unroll
    for (int ctile = 0; ctile < 4; ++ctile) {
      int oA = offA + (ctile << 5);
      int oB = offB + (ctile << 5);
      gload16(srcA0 + oA, dA0);
      gload16(srcA1 + oA, dA1);
      gload16(srcB0 + oB, dB0);
      gload16(srcB1 + oB, dB1);
      __syncthreads();  // drains vmcnt -> LDS tiles ready
      bf16x8 a[4], bb[4];
#pragma unroll
      for (int m = 0; m < 4; ++m)
        a[m] = *(const bf16x8*)(ldsA + aoff + (m << 10));
#pragma unroll
      for (int n = 0; n < 4; ++n)
        bb[n] = *(const bf16x8*)(ldsB + boff + (n << 10));
#pragma unroll
      for (int m = 0; m < 4; ++m)
#pragma unroll
        for (int n = 0; n < 4; ++n)
          acc[m][n] =
              __builtin_amdgcn_mfma_f32_16x16x32_bf16(a[m], bb[n], acc[m][n], 0, 0, 0);
      __syncthreads();  // reads done before next stage overwrites
    }
  }

  // epilogue: D[row=(l>>4)*4+q][col=l&15]; row->k, col->p
  int kb = mt * 128 + (wr << 6) + (hi << 2);
  int pb = (pt << 7) + (wc << 6) + r15;
#pragma unroll
  for (int m = 0; m < 4; ++m) {
    int kk = kb + (m << 4);
    float4 bv = *(const float4*)(bias + kk);
#pragma unroll
    for (int n = 0; n < 4; ++n) {
      int p = pb + (n << 4);
      int ni = p / 3136;
      int hw = p - ni * 3136;
      int base = (ni * 256 + kk) * 3136 + hw;
      f32x4 v = acc[m][n];
      out[base] = v[0] + bv.x;
      out[base + 3136] = v[1] + bv.y;
      out[base + 6272] = v[2] + bv.z;
      out[base + 9408] = v[3] + bv.w;
    }
  }
}

// ---- fallback: exact fp32 direct conv (only if ws too small) -----------
__global__ void conv_naive(const float* __restrict__ x, const float* __restrict__ flt,
                           const float* __restrict__ bias, float* __restrict__ out) {
  int idx = blockIdx.x * 256 + threadIdx.x;
  if (idx >= 32 * 256 * 3136) return;
  int hw = idx % 3136;
  int k = (idx / 3136) & 255;
  int n = idx / (3136 * 256);
  int h = hw / 56, w = hw % 56;
  float acc = bias[k];
  for (int c = 0; c < 128; ++c) {
    const float* xc = x + (n * 128 + c) * 3136;
    const float* fc = flt + (k * 128 + c) * 9;
#pragma unroll
    for (int r = 0; r < 3; ++r) {
      int hh = h + r - 1;
      if ((unsigned)hh >= 56u) continue;
#pragma unroll
      for (int s = 0; s < 3; ++s) {
        int ww = w + s - 1;
        if ((unsigned)ww >= 56u) continue;
        acc += xc[hh * 56 + ww] * fc[r * 3 + s];
      }
    }
  }
  out[idx] = acc;
}

extern "C" void kernel_launch(void* const* d_in, const int* in_sizes, int n_in,
                              void* d_out, int out_size, void* d_ws, size_t ws_size,
                              hipStream_t stream) {
  const float* x = (const float*)d_in[0];
  const float* flt = (const float*)d_in[1];
  const float* bias = (const float*)d_in[2];
  float* out = (float*)d_out;

  size_t need = (size_t)XP_BYTES + (size_t)WT_ELEMS * 2;
  if (ws_size < need) {
    conv_naive<<<(32 * 256 * 3136 + 255) / 256, 256, 0, stream>>>(x, flt, bias, out);
    return;
  }

  unsigned short* xp = (unsigned short*)d_ws;
  unsigned short* wtb = (unsigned short*)((char*)d_ws + XP_BYTES);

  hipMemsetAsync(d_ws, 0, XP_BYTES, stream);          // zero padding border
  prep_x<<<32 * 4 * 49, 256, 0, stream>>>(x, xp);     // 6272 blocks
  prep_w<<<WT_ELEMS / 256, 256, 0, stream>>>(flt, wtb);
  conv_mfma<<<2 * 784, 256, 0, stream>>>(xp, wtb, bias, out);
}

// Round 2
// 106.623 us; speedup vs baseline: 1.0971x; 1.0971x over previous
//
#include <hip/hip_runtime.h>
#include <hip/hip_bf16.h>
#include <cstdint>

// Conv2d 3x3 s1 p1, NCHW fp32 -> implicit GEMM on bf16 MFMA.
// x: [32][128][56][56] f32, filters: [256][128][3][3] f32, biases: [256] f32
// out: [32][256][56][56] f32
// ws: Xp (NHWC padded bf16 [32][58][58][128]) then Wt (bf16 [9][256][128]).
//
// Main loop: ring-of-5 LDS slots (16KB each = A 8KB + B 8KB), prefetch
// distance 2, counted s_waitcnt vmcnt(4) + raw s_barrier (no drain).
// Slot written at step t was last read at step t-3 (3 barriers earlier).

typedef __bf16 bf16x8 __attribute__((ext_vector_type(8)));
typedef float f32x4 __attribute__((ext_vector_type(4)));

#define XP_ELEMS (32 * 430592)            // 58*58*128 per image
#define XP_BYTES (XP_ELEMS * 2)           // 27,557,888
#define WT_ELEMS (9 * 256 * 128)          // 294,912

__device__ __forceinline__ unsigned short f2bf(float f) {
  __bf16 b = (__bf16)f;
  return __builtin_bit_cast(unsigned short, b);
}

__device__ __forceinline__ void gload16(const void* g, void* l) {
  __builtin_amdgcn_global_load_lds(
      (const __attribute__((address_space(1))) unsigned int*)g,
      (__attribute__((address_space(3))) unsigned int*)l,
      16, 0, 0);
}

// ---- prep: x NCHW f32 -> padded NHWC bf16 ------------------------------
__global__ __launch_bounds__(256) void prep_x(const float* __restrict__ x,
                                              unsigned short* __restrict__ xp) {
  __shared__ unsigned short lt[64][34];  // [hw][c] tile, padded stride
  int b = blockIdx.x;
  int hwt = b % 49;          // 49 tiles of 64 hw positions
  int ct  = (b / 49) & 3;    // 4 tiles of 32 channels
  int n   = b / 196;
  int t = threadIdx.x;
  int c_loc = t >> 3, col8 = t & 7;
  int hw0 = hwt << 6, c0 = ct << 5;

  const float* src = x + ((n * 128 + c0 + c_loc) * 3136 + hw0 + (col8 << 3));
  float4 v0 = *(const float4*)src;
  float4 v1 = *(const float4*)(src + 4);
  int hb = col8 << 3;
  lt[hb + 0][c_loc] = f2bf(v0.x);
  lt[hb + 1][c_loc] = f2bf(v0.y);
  lt[hb + 2][c_loc] = f2bf(v0.z);
  lt[hb + 3][c_loc] = f2bf(v0.w);
  lt[hb + 4][c_loc] = f2bf(v1.x);
  lt[hb + 5][c_loc] = f2bf(v1.y);
  lt[hb + 6][c_loc] = f2bf(v1.z);
  lt[hb + 7][c_loc] = f2bf(v1.w);
  __syncthreads();

  int hwl = t >> 2, cs = t & 3;
  const unsigned int* lr = (const unsigned int*)&lt[hwl][cs << 3];
  uint4 o = make_uint4(lr[0], lr[1], lr[2], lr[3]);
  int hw = hw0 + hwl;
  int hp = hw / 56 + 1, wp = hw % 56 + 1;
  unsigned short* dst = xp + (n * 430592 + (hp * 58 + wp) * 128 + c0 + (cs << 3));
  *(uint4*)dst = o;
}

// ---- prep: zero the padding border of Xp (replaces 27.5MB memset) ------
// Per image: rows 0 & 57 (928 uint4 each), plus cols 0 & 57 for rows 1-56
// (112 runs of 16 uint4). 3648 uint4 per image, 32 images = 116736 uint4.
__global__ __launch_bounds__(256) void border_zero(unsigned short* __restrict__ xp) {
  int idx = blockIdx.x * 256 + threadIdx.x;   // grid sized exactly 116736
  int img = idx / 3648;
  int j = idx - img * 3648;
  int u4off;
  if (j < 928) {
    u4off = j;                      // row hp=0
  } else if (j < 1856) {
    u4off = 52896 + (j - 928);      // row hp=57 (3306*16)
  } else {
    int k = j - 1856;
    int hp = 1 + (k >> 5);
    int r = k & 31;
    int wp = (r < 16) ? 0 : 57;
    u4off = (hp * 58 + wp) * 16 + (r & 15);
  }
  uint4 z = make_uint4(0u, 0u, 0u, 0u);
  *((uint4*)xp + img * 53824 + u4off) = z;    // 430592/8 = 53824
}

// ---- prep: filters OIHW f32 -> Wt[9][256][128] bf16 --------------------
__global__ __launch_bounds__(256) void prep_w(const float* __restrict__ f,
                                              unsigned short* __restrict__ wt) {
  int idx = blockIdx.x * 256 + threadIdx.x;  // < 294912
  int c = idx & 127;
  int k = (idx >> 7) & 255;
  int rs = idx >> 15;
  wt[idx] = f2bf(f[(k * 128 + c) * 9 + rs]);
}

// ---- main: implicit GEMM, ring-5 pipelined -----------------------------
// Block: 256 thr = 4 waves (2x2), tile BM=128 (k) x BN=128 (p). K-step 32.
__global__ __launch_bounds__(256, 2) void conv_mfma(const unsigned short* __restrict__ xp,
                                                    const unsigned short* __restrict__ wt,
                                                    const float* __restrict__ bias,
                                                    float* __restrict__ out) {
  __shared__ unsigned short lds5[5 * 8192];  // 5 slots x 16KB (A 8KB | B 8KB)
  char* ldsc = (char*)lds5;
  int bid = blockIdx.x;
  int mt = bid & 1;         // 2 M-tiles
  int pt = bid >> 1;        // 784 P-tiles
  int t = threadIdx.x;
  int wv = t >> 6, l = t & 63;

  // staging: each lane loads 16B; row = wv*16 + l/4 (+64 for chunk 1), slot = l&3.
  // LDS slot s holds DATA[row][s ^ f(row)], f(row)=(row>>1)&3 -> pre-swizzle source.
  int rowA0 = (wv << 4) + (l >> 2);
  int rowA1 = rowA0 + 64;
  int slot = l & 3;
  int sd0 = slot ^ ((rowA0 >> 1) & 3);
  int sd1 = slot ^ ((rowA1 >> 1) & 3);

  const unsigned short* srcA0 = wt + ((mt * 128 + rowA0) << 7) + (sd0 << 3);
  const unsigned short* srcA1 = wt + ((mt * 128 + rowA1) << 7) + (sd1 << 3);

  int pB0 = (pt << 7) + rowA0;
  int pB1 = pB0 + 64;
  int n0 = pB0 / 3136, hw0 = pB0 % 3136;
  int n1 = pB1 / 3136, hw1 = pB1 % 3136;
  const unsigned short* srcB0 =
      xp + (n0 * 430592 + ((hw0 / 56) * 58 + (hw0 % 56)) * 128 + (sd0 << 3));
  const unsigned short* srcB1 =
      xp + (n1 * 430592 + ((hw1 / 56) * 58 + (hw1 % 56)) * 128 + (sd1 << 3));

  int stW = wv << 10;  // wave's 1KB staging chunk within a region

  // fragment reads: row = base + (l&15), slot_read = (l>>4) ^ f(row)
  int r15 = l & 15, hi = l >> 4;
  int srd = hi ^ ((r15 >> 1) & 3);
  int wr = wv >> 1, wc = wv & 1;
  int aoff = ((wr << 6) + r15) * 64 + (srd << 4);           // + m*1024
  int boff = 8192 + ((wc << 6) + r15) * 64 + (srd << 4);    // + n*1024

  f32x4 acc[4][4];
#pragma unroll
  for (int m = 0; m < 4; ++m)
#pragma unroll
    for (int n = 0; n < 4; ++n) acc[m][n] = (f32x4){0.f, 0.f, 0.f, 0.f};

#define STAGE(sbyte, oA, oB)                                         \
  do {                                                               \
    gload16(srcA0 + (oA), ldsc + (sbyte) + stW);                     \
    gload16(srcA1 + (oA), ldsc + (sbyte) + 4096 + stW);              \
    gload16(srcB0 + (oB), ldsc + (sbyte) + 8192 + stW);              \
    gload16(srcB1 + (oB), ldsc + (sbyte) + 12288 + stW);             \
  } while (0)

  // prologue: stage steps 0,1 into slots 0,1 (step t: rs=t/4, ct=t%4;
  // oA = rs*32768 + ct*32, oB = rowoff(rs)*128 + ct*32)
  STAGE(0, 0, 0);
  STAGE(16384, 32, 32);
  asm volatile("s_waitcnt vmcnt(4)");   // slot0's 4 loads done
  __builtin_amdgcn_s_barrier();

  int sC = 0, sS = 2;
  int rs2 = 0, ct2 = 2;        // indices of step t+2
  int oA2 = 64, oB2 = 64;

#pragma unroll 1
  for (int tt = 0; tt < 36; ++tt) {
    STAGE(sS << 14, oA2, oB2);           // stage t+2 (clamped dummy at tail)
    int cb = sC << 14;
    bf16x8 a0 = *(const bf16x8*)(ldsc + cb + aoff);
    bf16x8 a1 = *(const bf16x8*)(ldsc + cb + aoff + 1024);
    bf16x8 a2 = *(const bf16x8*)(ldsc + cb + aoff + 2048);
    bf16x8 a3 = *(const bf16x8*)(ldsc + cb + aoff + 3072);
    bf16x8 b0 = *(const bf16x8*)(ldsc + cb + boff);
    bf16x8 b1 = *(const bf16x8*)(ldsc + cb + boff + 1024);
    bf16x8 b2 = *(const bf16x8*)(ldsc + cb + boff + 2048);
    bf16x8 b3 = *(const bf16x8*)(ldsc + cb + boff + 3072);
    __builtin_amdgcn_s_setprio(1);
    acc[0][0] = __builtin_amdgcn_mfma_f32_16x16x32_bf16(a0, b0, acc[0][0], 0, 0, 0);
    acc[0][1] = __builtin_amdgcn_mfma_f32_16x16x32_bf16(a0, b1, acc[0][1], 0, 0, 0);
    acc[0][2] = __builtin_amdgcn_mfma_f32_16x16x32_bf16(a0, b2, acc[0][2], 0, 0, 0);
    acc[0][3] = __builtin_amdgcn_mfma_f32_16x16x32_bf16(a0, b3, acc[0][3], 0, 0, 0);
    acc[1][0] = __builtin_amdgcn_mfma_f32_16x16x32_bf16(a1, b0, acc[1][0], 0, 0, 0);
    acc[1][1] = __builtin_amdgcn_mfma_f32_16x16x32_bf16(a1, b1, acc[1][1], 0, 0, 0);
    acc[1][2] = __builtin_amdgcn_mfma_f32_16x16x32_bf16(a1, b2, acc[1][2], 0, 0, 0);
    acc[1][3] = __builtin_amdgcn_mfma_f32_16x16x32_bf16(a1, b3, acc[1][3], 0, 0, 0);
    acc[2][0] = __builtin_amdgcn_mfma_f32_16x16x32_bf16(a2, b0, acc[2][0], 0, 0, 0);
    acc[2][1] = __builtin_amdgcn_mfma_f32_16x16x32_bf16(a2, b1, acc[2][1], 0, 0, 0);
    acc[2][2] = __builtin_amdgcn_mfma_f32_16x16x32_bf16(a2, b2, acc[2][2], 0, 0, 0);
    acc[2][3] = __builtin_amdgcn_mfma_f32_16x16x32_bf16(a2, b3, acc[2][3], 0, 0, 0);
    acc[3][0] = __builtin_amdgcn_mfma_f32_16x16x32_bf16(a3, b0, acc[3][0], 0, 0, 0);
    acc[3][1] = __builtin_amdgcn_mfma_f32_16x16x32_bf16(a3, b1, acc[3][1], 0, 0, 0);
    acc[3][2] = __builtin_amdgcn_mfma_f32_16x16x32_bf16(a3, b2, acc[3][2], 0, 0, 0);
    acc[3][3] = __builtin_amdgcn_mfma_f32_16x16x32_bf16(a3, b3, acc[3][3], 0, 0, 0);
    __builtin_amdgcn_s_setprio(0);
    // wait only t+1's 4 loads (issued last step); t+2's 4 stay in flight
    asm volatile("s_waitcnt vmcnt(4)");
    __builtin_amdgcn_s_barrier();
    sC = (sC == 4) ? 0 : sC + 1;
    sS = (sS == 4) ? 0 : sS + 1;
    if (tt < 33) {               // prepare offsets for target step tt+3 (<=35)
      if (ct2 == 3) {
        ct2 = 0;
        ++rs2;
        oA2 = rs2 << 15;
        int r3 = (rs2 * 43) >> 7;                       // rs2/3 for rs2<9
        oB2 = (r3 * 58 + (rs2 - r3 * 3)) << 7;
      } else {
        ++ct2;
        oA2 += 32;
        oB2 += 32;
      }
    }
  }
#undef STAGE

  // epilogue: D[row=(l>>4)*4+q][col=l&15]; row->k, col->p
  int kb = mt * 128 + (wr << 6) + (hi << 2);
  int pb = (pt << 7) + (wc << 6) + r15;
#pragma unroll
  for (int m = 0; m < 4; ++m) {
    int kk = kb + (m << 4);
    float4 bv = *(const float4*)(bias + kk);
#pragma unroll
    for (int n = 0; n < 4; ++n) {
      int p = pb + (n << 4);
      int ni = p / 3136;
      int hw = p - ni * 3136;
      int base = (ni * 256 + kk) * 3136 + hw;
      f32x4 v = acc[m][n];
      out[base] = v[0] + bv.x;
      out[base + 3136] = v[1] + bv.y;
      out[base + 6272] = v[2] + bv.z;
      out[base + 9408] = v[3] + bv.w;
    }
  }
}

// ---- fallback: exact fp32 direct conv (only if ws too small) -----------
__global__ void conv_naive(const float* __restrict__ x, const float* __restrict__ flt,
                           const float* __restrict__ bias, float* __restrict__ out) {
  int idx = blockIdx.x * 256 + threadIdx.x;
  if (idx >= 32 * 256 * 3136) return;
  int hw = idx % 3136;
  int k = (idx / 3136) & 255;
  int n = idx / (3136 * 256);
  int h = hw / 56, w = hw % 56;
  float acc = bias[k];
  for (int c = 0; c < 128; ++c) {
    const float* xc = x + (n * 128 + c) * 3136;
    const float* fc = flt + (k * 128 + c) * 9;
#pragma unroll
    for (int r = 0; r < 3; ++r) {
      int hh = h + r - 1;
      if ((unsigned)hh >= 56u) continue;
#pragma unroll
      for (int s = 0; s < 3; ++s) {
        int ww = w + s - 1;
        if ((unsigned)ww >= 56u) continue;
        acc += xc[hh * 56 + ww] * fc[r * 3 + s];
      }
    }
  }
  out[idx] = acc;
}

extern "C" void kernel_launch(void* const* d_in, const int* in_sizes, int n_in,
                              void* d_out, int out_size, void* d_ws, size_t ws_size,
                              hipStream_t stream) {
  const float* x = (const float*)d_in[0];
  const float* flt = (const float*)d_in[1];
  const float* bias = (const float*)d_in[2];
  float* out = (float*)d_out;

  size_t need = (size_t)XP_BYTES + (size_t)WT_ELEMS * 2;
  if (ws_size < need) {
    conv_naive<<<(32 * 256 * 3136 + 255) / 256, 256, 0, stream>>>(x, flt, bias, out);
    return;
  }

  unsigned short* xp = (unsigned short*)d_ws;
  unsigned short* wtb = (unsigned short*)((char*)d_ws + XP_BYTES);

  border_zero<<<456, 256, 0, stream>>>(xp);           // 456*256 = 116736 exactly
  prep_x<<<32 * 4 * 49, 256, 0, stream>>>(x, xp);     // 6272 blocks
  prep_w<<<WT_ELEMS / 256, 256, 0, stream>>>(flt, wtb);
  conv_mfma<<<2 * 784, 256, 0, stream>>>(xp, wtb, bias, out);
}

// Round 3
// 93.466 us; speedup vs baseline: 1.2516x; 1.1408x over previous
//
#include <hip/hip_runtime.h>
#include <hip/hip_bf16.h>
#include <cstdint>

// Conv2d 3x3 s1 p1, NCHW fp32 -> implicit GEMM on bf16 MFMA.
// x: [32][128][56][56] f32, filters: [256][128][3][3] f32, biases: [256] f32
// out: [32][256][56][56] f32
// ws: Xp (NHWC padded bf16 [32][58][58][128]) then Wt (bf16 [9][256][128]).
//
// Block tile 128(M=k)x256(N=pix), 4 waves 2x2, per-wave 64x128 (4x8 frags).
// Ring-3 LDS slots (24KB = A 8KB | B 16KB), prefetch distance 2,
// counted s_waitcnt vmcnt(6) + raw s_barrier. Slot written at step t was
// last read at step t-1, separated by the end-of-(t-1) barrier.

typedef __bf16 bf16x8 __attribute__((ext_vector_type(8)));
typedef float f32x4 __attribute__((ext_vector_type(4)));

#define XP_ELEMS (32 * 430592)            // 58*58*128 per image
#define XP_BYTES (XP_ELEMS * 2)           // 27,557,888
#define WT_ELEMS (9 * 256 * 128)          // 294,912

__device__ __forceinline__ unsigned short f2bf(float f) {
  __bf16 b = (__bf16)f;
  return __builtin_bit_cast(unsigned short, b);
}

__device__ __forceinline__ void gload16(const void* g, void* l) {
  __builtin_amdgcn_global_load_lds(
      (const __attribute__((address_space(1))) unsigned int*)g,
      (__attribute__((address_space(3))) unsigned int*)l,
      16, 0, 0);
}

// ---- prep: x NCHW f32 -> padded NHWC bf16 ------------------------------
__global__ __launch_bounds__(256) void prep_x(const float* __restrict__ x,
                                              unsigned short* __restrict__ xp) {
  __shared__ unsigned short lt[64][34];  // [hw][c] tile, padded stride
  int b = blockIdx.x;
  int hwt = b % 49;          // 49 tiles of 64 hw positions
  int ct  = (b / 49) & 3;    // 4 tiles of 32 channels
  int n   = b / 196;
  int t = threadIdx.x;
  int c_loc = t >> 3, col8 = t & 7;
  int hw0 = hwt << 6, c0 = ct << 5;

  const float* src = x + ((n * 128 + c0 + c_loc) * 3136 + hw0 + (col8 << 3));
  float4 v0 = *(const float4*)src;
  float4 v1 = *(const float4*)(src + 4);
  int hb = col8 << 3;
  lt[hb + 0][c_loc] = f2bf(v0.x);
  lt[hb + 1][c_loc] = f2bf(v0.y);
  lt[hb + 2][c_loc] = f2bf(v0.z);
  lt[hb + 3][c_loc] = f2bf(v0.w);
  lt[hb + 4][c_loc] = f2bf(v1.x);
  lt[hb + 5][c_loc] = f2bf(v1.y);
  lt[hb + 6][c_loc] = f2bf(v1.z);
  lt[hb + 7][c_loc] = f2bf(v1.w);
  __syncthreads();

  int hwl = t >> 2, cs = t & 3;
  const unsigned int* lr = (const unsigned int*)&lt[hwl][cs << 3];
  uint4 o = make_uint4(lr[0], lr[1], lr[2], lr[3]);
  int hw = hw0 + hwl;
  int hp = hw / 56 + 1, wp = hw % 56 + 1;
  unsigned short* dst = xp + (n * 430592 + (hp * 58 + wp) * 128 + c0 + (cs << 3));
  *(uint4*)dst = o;
}

// ---- prep: zero the padding border of Xp -------------------------------
__global__ __launch_bounds__(256) void border_zero(unsigned short* __restrict__ xp) {
  int idx = blockIdx.x * 256 + threadIdx.x;   // grid sized exactly 116736
  int img = idx / 3648;
  int j = idx - img * 3648;
  int u4off;
  if (j < 928) {
    u4off = j;                      // row hp=0
  } else if (j < 1856) {
    u4off = 52896 + (j - 928);      // row hp=57
  } else {
    int k = j - 1856;
    int hp = 1 + (k >> 5);
    int r = k & 31;
    int wp = (r < 16) ? 0 : 57;
    u4off = (hp * 58 + wp) * 16 + (r & 15);
  }
  uint4 z = make_uint4(0u, 0u, 0u, 0u);
  *((uint4*)xp + img * 53824 + u4off) = z;
}

// ---- prep: filters OIHW f32 -> Wt[9][256][128] bf16 --------------------
__global__ __launch_bounds__(256) void prep_w(const float* __restrict__ f,
                                              unsigned short* __restrict__ wt) {
  int idx = blockIdx.x * 256 + threadIdx.x;  // < 294912
  int c = idx & 127;
  int k = (idx >> 7) & 255;
  int rs = idx >> 15;
  wt[idx] = f2bf(f[(k * 128 + c) * 9 + rs]);
}

// ---- main: implicit GEMM, 128x256 tile, ring-3 pipelined ---------------
__global__ __launch_bounds__(256, 2) void conv_mfma(const unsigned short* __restrict__ xp,
                                                    const unsigned short* __restrict__ wt,
                                                    const float* __restrict__ bias,
                                                    float* __restrict__ out) {
  __shared__ unsigned short lds3[3 * 12288];  // 3 slots x 24KB (A 8KB | B 16KB)
  char* ldsc = (char*)lds3;
  int bid = blockIdx.x;
  // XCD-aware swizzle: 784 = 8*98; both mt of a pt land adjacent on one XCD.
  int sw = (bid & 7) * 98 + (bid >> 3);
  int mt = sw & 1;          // 2 M-tiles (k 0..127 / 128..255)
  int pt = sw >> 1;         // 392 pixel tiles of 256
  int t = threadIdx.x;
  int wv = t >> 6, l = t & 63;

  // staging: rows row0=t>>2 (+64 per chunk), 16B slot = t&3, pre-swizzled
  // source slot sd = slot ^ f(row), f(row)=(row>>1)&3 (invariant to +64).
  int row0 = t >> 2;
  int slot = t & 3;
  int sd = slot ^ ((row0 >> 1) & 3);

  const unsigned short* srcA0 = wt + ((mt * 128 + row0) << 7) + (sd << 3);
  const unsigned short* srcA1 = srcA0 + (64 << 7);

  const unsigned short* srcB[4];
#pragma unroll
  for (int c = 0; c < 4; ++c) {
    int p = (pt << 8) + row0 + (c << 6);
    int n = p / 3136, hw = p % 3136;
    srcB[c] = xp + (n * 430592 + ((hw / 56) * 58 + (hw % 56)) * 128 + (sd << 3));
  }
  const unsigned short* srcB0 = srcB[0];
  const unsigned short* srcB1 = srcB[1];
  const unsigned short* srcB2 = srcB[2];
  const unsigned short* srcB3 = srcB[3];

  int stW = wv << 10;  // wave's 1KB contiguous chunk within a region

  // fragment reads: data slot (l>>4) of row r -> LDS slot (l>>4)^f(r)
  int r15 = l & 15, hi = l >> 4;
  int srd = hi ^ ((r15 >> 1) & 3);
  int wr = wv >> 1, wc = wv & 1;
  int aoff = (wr << 12) + (r15 << 6) + (srd << 4);           // + m*1024
  int boff = 8192 + (wc << 13) + (r15 << 6) + (srd << 4);    // + n*1024

  f32x4 acc[4][8];
#pragma unroll
  for (int m = 0; m < 4; ++m)
#pragma unroll
    for (int n = 0; n < 8; ++n) acc[m][n] = (f32x4){0.f, 0.f, 0.f, 0.f};

#define STAGE(sbyte, oA, oB)                                       \
  do {                                                             \
    gload16(srcA0 + (oA), ldsc + (sbyte) + stW);                   \
    gload16(srcA1 + (oA), ldsc + (sbyte) + 4096 + stW);            \
    gload16(srcB0 + (oB), ldsc + (sbyte) + 8192 + stW);            \
    gload16(srcB1 + (oB), ldsc + (sbyte) + 12288 + stW);           \
    gload16(srcB2 + (oB), ldsc + (sbyte) + 16384 + stW);           \
    gload16(srcB3 + (oB), ldsc + (sbyte) + 20480 + stW);           \
  } while (0)

  // step t: rs=t/4, ct=t%4; oA = rs*32768 + ct*32, oB = ((rs/3)*58+rs%3)*128 + ct*32
  STAGE(0, 0, 0);          // step 0 -> slot 0
  STAGE(24576, 32, 32);    // step 1 -> slot 1
  asm volatile("s_waitcnt vmcnt(6)" ::: "memory");  // slot 0 ready
  __builtin_amdgcn_s_barrier();

  int sC = 0, sS = 2;          // consume slot, stage slot (ring-3)
  int rs2 = 0, ct2 = 2;        // indices of step t+2
  int oA2 = 64, oB2 = 64;

#pragma unroll 1
  for (int tt = 0; tt < 36; ++tt) {
    STAGE(sS * 24576, oA2, oB2);         // stage t+2 (harmless dummy at tail)
    int cb = sC * 24576;
    bf16x8 a[4], b[8];
#pragma unroll
    for (int m = 0; m < 4; ++m)
      a[m] = *(const bf16x8*)(ldsc + cb + aoff + (m << 10));
#pragma unroll
    for (int n = 0; n < 8; ++n)
      b[n] = *(const bf16x8*)(ldsc + cb + boff + (n << 10));
    __builtin_amdgcn_s_setprio(1);
#pragma unroll
    for (int m = 0; m < 4; ++m)
#pragma unroll
      for (int n = 0; n < 8; ++n)
        acc[m][n] =
            __builtin_amdgcn_mfma_f32_16x16x32_bf16(a[m], b[n], acc[m][n], 0, 0, 0);
    __builtin_amdgcn_s_setprio(0);
    // drain t+1's 6 loads (issued last step); t+2's 6 stay in flight
    asm volatile("s_waitcnt vmcnt(6)" ::: "memory");
    __builtin_amdgcn_s_barrier();
    sC = (sC == 2) ? 0 : sC + 1;
    sS = (sS == 2) ? 0 : sS + 1;
    if (tt < 33) {               // advance offsets to step tt+3 (<=35)
      if (ct2 == 3) {
        ct2 = 0;
        ++rs2;
        oA2 = rs2 << 15;
        int r3 = (rs2 * 43) >> 7;                       // rs2/3 for rs2<9
        oB2 = (r3 * 58 + (rs2 - r3 * 3)) << 7;
      } else {
        ++ct2;
        oA2 += 32;
        oB2 += 32;
      }
    }
  }
#undef STAGE

  // epilogue: D[row=(l>>4)*4+q][col=l&15]; row->k, col->pixel
  int kb = mt * 128 + (wr << 6) + (hi << 2);
  int pb = (pt << 8) + (wc << 7) + r15;
#pragma unroll
  for (int m = 0; m < 4; ++m) {
    int kk = kb + (m << 4);
    float4 bv = *(const float4*)(bias + kk);
#pragma unroll
    for (int n = 0; n < 8; ++n) {
      int p = pb + (n << 4);
      int ni = p / 3136;
      int hw = p - ni * 3136;
      int base = (ni * 256 + kk) * 3136 + hw;
      f32x4 v = acc[m][n];
      out[base] = v[0] + bv.x;
      out[base + 3136] = v[1] + bv.y;
      out[base + 6272] = v[2] + bv.z;
      out[base + 9408] = v[3] + bv.w;
    }
  }
}

// ---- fallback: exact fp32 direct conv (only if ws too small) -----------
__global__ void conv_naive(const float* __restrict__ x, const float* __restrict__ flt,
                           const float* __restrict__ bias, float* __restrict__ out) {
  int idx = blockIdx.x * 256 + threadIdx.x;
  if (idx >= 32 * 256 * 3136) return;
  int hw = idx % 3136;
  int k = (idx / 3136) & 255;
  int n = idx / (3136 * 256);
  int h = hw / 56, w = hw % 56;
  float acc = bias[k];
  for (int c = 0; c < 128; ++c) {
    const float* xc = x + (n * 128 + c) * 3136;
    const float* fc = flt + (k * 128 + c) * 9;
#pragma unroll
    for (int r = 0; r < 3; ++r) {
      int hh = h + r - 1;
      if ((unsigned)hh >= 56u) continue;
#pragma unroll
      for (int s = 0; s < 3; ++s) {
        int ww = w + s - 1;
        if ((unsigned)ww >= 56u) continue;
        acc += xc[hh * 56 + ww] * fc[r * 3 + s];
      }
    }
  }
  out[idx] = acc;
}

extern "C" void kernel_launch(void* const* d_in, const int* in_sizes, int n_in,
                              void* d_out, int out_size, void* d_ws, size_t ws_size,
                              hipStream_t stream) {
  const float* x = (const float*)d_in[0];
  const float* flt = (const float*)d_in[1];
  const float* bias = (const float*)d_in[2];
  float* out = (float*)d_out;

  size_t need = (size_t)XP_BYTES + (size_t)WT_ELEMS * 2;
  if (ws_size < need) {
    conv_naive<<<(32 * 256 * 3136 + 255) / 256, 256, 0, stream>>>(x, flt, bias, out);
    return;
  }

  unsigned short* xp = (unsigned short*)d_ws;
  unsigned short* wtb = (unsigned short*)((char*)d_ws + XP_BYTES);

  border_zero<<<456, 256, 0, stream>>>(xp);           // 456*256 = 116736 exactly
  prep_x<<<32 * 4 * 49, 256, 0, stream>>>(x, xp);     // 6272 blocks
  prep_w<<<WT_ELEMS / 256, 256, 0, stream>>>(flt, wtb);
  conv_mfma<<<784, 256, 0, stream>>>(xp, wtb, bias, out);
}